// Round 1
// baseline (5215.883 us; speedup 1.0000x reference)
//
#include <hip/hip_runtime.h>

#define T_LEN 3000
#define BATCH 64
#define G4 100   // 4*H, H=25

// ---------------------------------------------------------------------------
// GEMM: xg[dir][t][b][j] = (b_ih+b_hh)[dir][j] + sum_k in_row(t,b)[k]*w_ih[dir][j][k]
// MODE 0: input is x with layout (B,T,F); MODE 1: input layout (T,B,K)
// grid: (T_LEN*BATCH/64, 2), block: 256 (4 waves; wave w owns cols [25w,25w+25))
// ---------------------------------------------------------------------------
template <int MODE>
__global__ __launch_bounds__(256) void gemm_xg(
    const float* __restrict__ in, const float* __restrict__ w_ih,
    const float* __restrict__ b_ih, const float* __restrict__ b_hh,
    float* __restrict__ xg, int K) {
  __shared__ __align__(16) float lds_x[64][33];   // pad 33: (lane+k)%32 -> 2-way max (free)
  __shared__ __align__(16) float lds_w[100][32];  // rows 128B-aligned for float4 reads

  const int tid = threadIdx.x;
  const int dir = blockIdx.y;
  const int r0 = blockIdx.x * 64;
  const int lane = tid & 63;
  const int wv = tid >> 6;
  const int c0 = wv * 25;
  const float* wbase = w_ih + (size_t)dir * G4 * K;

  float acc[25];
#pragma unroll
  for (int c = 0; c < 25; ++c)
    acc[c] = b_ih[dir * G4 + c0 + c] + b_hh[dir * G4 + c0 + c];

  for (int k0 = 0; k0 < K; k0 += 32) {
    const int kw = min(32, K - k0);
    // stage x tile: 64 rows x 32 k
#pragma unroll
    for (int i = 0; i < 8; ++i) {
      int e = tid + i * 256;           // e in [0,2048)
      int rr = e >> 5, kk = e & 31;
      int grow = r0 + rr;
      const float* rp;
      if (MODE == 0) {
        int tt = grow >> 6, bb = grow & 63;   // row = t*64 + b
        rp = in + ((size_t)bb * T_LEN + tt) * K;
      } else {
        rp = in + (size_t)grow * K;
      }
      lds_x[rr][kk] = (kk < kw) ? rp[k0 + kk] : 0.f;
    }
    // stage w tile: 100 rows x 32 k
#pragma unroll
    for (int i = 0; i < 13; ++i) {
      int e = tid + i * 256;
      if (e < 3200) {
        int j = e >> 5, kk = e & 31;
        lds_w[j][kk] = (kk < kw) ? wbase[(size_t)j * K + k0 + kk] : 0.f;
      }
    }
    __syncthreads();
#pragma unroll 2
    for (int k4 = 0; k4 < 8; ++k4) {
      float xv0 = lds_x[lane][k4 * 4 + 0];
      float xv1 = lds_x[lane][k4 * 4 + 1];
      float xv2 = lds_x[lane][k4 * 4 + 2];
      float xv3 = lds_x[lane][k4 * 4 + 3];
#pragma unroll
      for (int c = 0; c < 25; ++c) {
        float4 w4 = *(const float4*)&lds_w[c0 + c][k4 * 4];  // wave-uniform -> broadcast
        acc[c] = fmaf(xv0, w4.x, acc[c]);
        acc[c] = fmaf(xv1, w4.y, acc[c]);
        acc[c] = fmaf(xv2, w4.z, acc[c]);
        acc[c] = fmaf(xv3, w4.w, acc[c]);
      }
    }
    __syncthreads();
  }
  // write: xg[dir][row][c0..c0+24]  (row = t*B+b)
  const int row = r0 + lane;
  float* orow = xg + ((size_t)dir * T_LEN * BATCH + row) * G4 + c0;
#pragma unroll
  for (int c = 0; c < 25; ++c) orow[c] = acc[c];
}

// ---------------------------------------------------------------------------
// Sequential LSTM scan: one wave per (b, dir). grid = 128 blocks x 64 threads.
// Lane n<25 owns cell n: holds w_hh rows {n, n+25, n+50, n+75} in registers,
// computes all 4 gates + c + h locally; h broadcast via 25-float LDS roundtrip
// (intra-wave: lgkmcnt wait only, NO s_barrier -> keeps xg prefetch in flight).
// ---------------------------------------------------------------------------
__device__ __forceinline__ float sigm(float x) { return 1.f / (1.f + __expf(-x)); }
__device__ __forceinline__ float tanh_f(float x) { return 1.f - 2.f / (__expf(2.f * x) + 1.f); }

__device__ __forceinline__ void lstm_step(
    float (&pf)[4], const float* __restrict__ nxt, int n,
    const float (&w)[4][25], float (&h)[25], float& c,
    float* h_lds, float* __restrict__ hout_ptr, int lane) {
  float p0 = pf[0], p1 = pf[1], p2 = pf[2], p3 = pf[3];
  // issue next step's xg prefetch before the dependent chain
  pf[0] = nxt[n]; pf[1] = nxt[n + 25]; pf[2] = nxt[n + 50]; pf[3] = nxt[n + 75];
#pragma unroll
  for (int k = 0; k < 25; ++k) {
    p0 = fmaf(w[0][k], h[k], p0);
    p1 = fmaf(w[1][k], h[k], p1);
    p2 = fmaf(w[2][k], h[k], p2);
    p3 = fmaf(w[3][k], h[k], p3);
  }
  float ig = sigm(p0), fg = sigm(p1), gg = tanh_f(p2), og = sigm(p3);
  c = fmaf(fg, c, ig * gg);
  float hn = og * tanh_f(c);
  if (lane < 25) {
    h_lds[lane] = hn;
    *hout_ptr = hn;
  }
  asm volatile("s_waitcnt lgkmcnt(0)" ::: "memory");
#pragma unroll
  for (int k = 0; k < 25; ++k) h[k] = h_lds[k];
}

__global__ __launch_bounds__(64) void lstm_scan(
    const float* __restrict__ xg,    // [2][T][B][100]
    const float* __restrict__ w_hh,  // [2][100][25]
    float* __restrict__ hout) {      // [T][B][50], this dir writes cols dir*25..+25
  const int dir = blockIdx.x & 1;
  const int b = blockIdx.x >> 1;
  const int lane = threadIdx.x;
  const int n = (lane < 25) ? lane : 0;
  __shared__ float h_lds[25];

  float w[4][25];
#pragma unroll
  for (int g = 0; g < 4; ++g)
#pragma unroll
    for (int k = 0; k < 25; ++k)
      w[g][k] = w_hh[((size_t)dir * 100 + n + 25 * g) * 25 + k];

  float h[25], c = 0.f;
#pragma unroll
  for (int k = 0; k < 25; ++k) h[k] = 0.f;

  const size_t dbase = (size_t)dir * T_LEN * BATCH * G4 + (size_t)b * G4;
  auto xaddr = [&](int s) {
    int tt = dir ? (T_LEN - 1 - s) : s;
    return xg + dbase + (size_t)tt * (BATCH * G4);
  };
  auto hptr = [&](int s) {
    int tt = dir ? (T_LEN - 1 - s) : s;
    return hout + ((size_t)tt * BATCH + b) * 50 + dir * 25 + n;
  };

  float pfA[4], pfB[4];
  {
    const float* a = xaddr(0);
    pfA[0] = a[n]; pfA[1] = a[n + 25]; pfA[2] = a[n + 50]; pfA[3] = a[n + 75];
  }
  {
    const float* a = xaddr(1);
    pfB[0] = a[n]; pfB[1] = a[n + 25]; pfB[2] = a[n + 50]; pfB[3] = a[n + 75];
  }

  for (int s = 0; s < T_LEN; s += 2) {
    lstm_step(pfA, xaddr(min(s + 2, T_LEN - 1)), n, w, h, c, h_lds, hptr(s), lane);
    lstm_step(pfB, xaddr(min(s + 3, T_LEN - 1)), n, w, h, c, h_lds, hptr(s + 1), lane);
  }
}

// ---------------------------------------------------------------------------
// FC: out[b][t][m] = sum_j h[t][b][j] * fc_w[m][j] + fc_b[m]
// ---------------------------------------------------------------------------
__global__ __launch_bounds__(256) void fc_kernel(
    const float* __restrict__ h, const float* __restrict__ fc_w,
    const float* __restrict__ fc_b, float* __restrict__ out) {
  int row = blockIdx.x * 256 + threadIdx.x;  // row = t*B + b
  if (row >= T_LEN * BATCH) return;
  int t = row >> 6, b = row & 63;
  const float* hr = h + (size_t)row * 50;
  float a0 = fc_b[0], a1 = fc_b[1], a2 = fc_b[2];
#pragma unroll
  for (int j = 0; j < 50; ++j) {
    float v = hr[j];
    a0 = fmaf(v, fc_w[j], a0);
    a1 = fmaf(v, fc_w[50 + j], a1);
    a2 = fmaf(v, fc_w[100 + j], a2);
  }
  float* op = out + ((size_t)b * T_LEN + t) * 3;
  op[0] = a0; op[1] = a1; op[2] = a2;
}

// ---------------------------------------------------------------------------
extern "C" void kernel_launch(void* const* d_in, const int* in_sizes, int n_in,
                              void* d_out, int out_size, void* d_ws, size_t ws_size,
                              hipStream_t stream) {
  const float* x = (const float*)d_in[0];
  const float* w_ih[3] = {(const float*)d_in[1], (const float*)d_in[5], (const float*)d_in[9]};
  const float* w_hh[3] = {(const float*)d_in[2], (const float*)d_in[6], (const float*)d_in[10]};
  const float* b_ih[3] = {(const float*)d_in[3], (const float*)d_in[7], (const float*)d_in[11]};
  const float* b_hh[3] = {(const float*)d_in[4], (const float*)d_in[8], (const float*)d_in[12]};
  const float* fc_w = (const float*)d_in[13];
  const float* fc_b = (const float*)d_in[14];
  float* out = (float*)d_out;

  float* xg = (float*)d_ws;                                 // 2*T*B*100 fp32 = 153.6 MB
  float* hA = xg + (size_t)2 * T_LEN * BATCH * G4;          // T*B*50 = 38.4 MB
  float* hB = hA + (size_t)T_LEN * BATCH * 50;              // T*B*50 = 38.4 MB

  dim3 gg(T_LEN * BATCH / 64, 2), gb(256);

  // layer 0
  hipLaunchKernelGGL((gemm_xg<0>), gg, gb, 0, stream, x, w_ih[0], b_ih[0], b_hh[0], xg, 314);
  hipLaunchKernelGGL(lstm_scan, dim3(2 * BATCH), dim3(64), 0, stream, xg, w_hh[0], hA);
  // layer 1
  hipLaunchKernelGGL((gemm_xg<1>), gg, gb, 0, stream, hA, w_ih[1], b_ih[1], b_hh[1], xg, 50);
  hipLaunchKernelGGL(lstm_scan, dim3(2 * BATCH), dim3(64), 0, stream, xg, w_hh[1], hB);
  // layer 2
  hipLaunchKernelGGL((gemm_xg<1>), gg, gb, 0, stream, hB, w_ih[2], b_ih[2], b_hh[2], xg, 50);
  hipLaunchKernelGGL(lstm_scan, dim3(2 * BATCH), dim3(64), 0, stream, xg, w_hh[2], hA);
  // fc
  hipLaunchKernelGGL(fc_kernel, dim3(T_LEN * BATCH / 256), dim3(256), 0, stream, hA, fc_w, fc_b, out);
}

// Round 2
// 3615.634 us; speedup vs baseline: 1.4426x; 1.4426x over previous
//
#include <hip/hip_runtime.h>

#define T_LEN 3000
#define BATCH 64
#define G4 100   // 4*H, H=25

// ---------------------------------------------------------------------------
// GEMM: xg[dir][t][b][j] = (b_ih+b_hh)[dir][j] + sum_k in_row(t,b)[k]*w_ih[dir][j][k]
// MODE 0: input is x with layout (B,T,F); MODE 1: input layout (T,B,K)
// grid: (T_LEN*BATCH/64, 2), block: 256 (4 waves; wave w owns cols [25w,25w+25))
// ---------------------------------------------------------------------------
template <int MODE>
__global__ __launch_bounds__(256) void gemm_xg(
    const float* __restrict__ in, const float* __restrict__ w_ih,
    const float* __restrict__ b_ih, const float* __restrict__ b_hh,
    float* __restrict__ xg, int K) {
  __shared__ __align__(16) float lds_x[64][33];   // pad 33: (lane+k)%32 -> 2-way max (free)
  __shared__ __align__(16) float lds_w[100][32];  // rows 128B-aligned for float4 reads

  const int tid = threadIdx.x;
  const int dir = blockIdx.y;
  const int r0 = blockIdx.x * 64;
  const int lane = tid & 63;
  const int wv = tid >> 6;
  const int c0 = wv * 25;
  const float* wbase = w_ih + (size_t)dir * G4 * K;

  float acc[25];
#pragma unroll
  for (int c = 0; c < 25; ++c)
    acc[c] = b_ih[dir * G4 + c0 + c] + b_hh[dir * G4 + c0 + c];

  for (int k0 = 0; k0 < K; k0 += 32) {
    const int kw = min(32, K - k0);
    // stage x tile: 64 rows x 32 k
#pragma unroll
    for (int i = 0; i < 8; ++i) {
      int e = tid + i * 256;           // e in [0,2048)
      int rr = e >> 5, kk = e & 31;
      int grow = r0 + rr;
      const float* rp;
      if (MODE == 0) {
        int tt = grow >> 6, bb = grow & 63;   // row = t*64 + b
        rp = in + ((size_t)bb * T_LEN + tt) * K;
      } else {
        rp = in + (size_t)grow * K;
      }
      lds_x[rr][kk] = (kk < kw) ? rp[k0 + kk] : 0.f;
    }
    // stage w tile: 100 rows x 32 k
#pragma unroll
    for (int i = 0; i < 13; ++i) {
      int e = tid + i * 256;
      if (e < 3200) {
        int j = e >> 5, kk = e & 31;
        lds_w[j][kk] = (kk < kw) ? wbase[(size_t)j * K + k0 + kk] : 0.f;
      }
    }
    __syncthreads();
#pragma unroll 2
    for (int k4 = 0; k4 < 8; ++k4) {
      float xv0 = lds_x[lane][k4 * 4 + 0];
      float xv1 = lds_x[lane][k4 * 4 + 1];
      float xv2 = lds_x[lane][k4 * 4 + 2];
      float xv3 = lds_x[lane][k4 * 4 + 3];
#pragma unroll
      for (int c = 0; c < 25; ++c) {
        float4 w4 = *(const float4*)&lds_w[c0 + c][k4 * 4];  // wave-uniform -> broadcast
        acc[c] = fmaf(xv0, w4.x, acc[c]);
        acc[c] = fmaf(xv1, w4.y, acc[c]);
        acc[c] = fmaf(xv2, w4.z, acc[c]);
        acc[c] = fmaf(xv3, w4.w, acc[c]);
      }
    }
    __syncthreads();
  }
  // write: xg[dir][row][c0..c0+24]  (row = t*B+b)
  const int row = r0 + lane;
  float* orow = xg + ((size_t)dir * T_LEN * BATCH + row) * G4 + c0;
#pragma unroll
  for (int c = 0; c < 25; ++c) orow[c] = acc[c];
}

// ---------------------------------------------------------------------------
// Fast activations: v_rcp_f32 (1 ulp) instead of exact divide sequences.
// ---------------------------------------------------------------------------
__device__ __forceinline__ float frcp(float x) { return __builtin_amdgcn_rcpf(x); }
__device__ __forceinline__ float sigm(float x) { return frcp(1.f + __expf(-x)); }
__device__ __forceinline__ float tanh_f(float x) { return 1.f - 2.f * frcp(__expf(2.f * x) + 1.f); }

// ---------------------------------------------------------------------------
// Sequential LSTM scan: one wave per (b, dir). grid = 128 blocks x 64 threads.
// Gate-split across 50 lanes: lane n in [0,25) owns gates (i_n, g_n);
// lane n+25 owns gates (f_n, o_n) and the cell state c_n.
// Per step: 50 fma (2 dots of 25 per lane), shared-exp activations,
// one __shfl to ship u = i*g to the c-owning lane, h broadcast via 25-float
// LDS roundtrip (intra-wave lgkmcnt wait only, no barrier).
// ---------------------------------------------------------------------------
__global__ __launch_bounds__(64, 1) void lstm_scan(
    const float* __restrict__ xg,    // [2][T][B][100]
    const float* __restrict__ w_hh,  // [2][100][25]
    float* __restrict__ hout) {      // [T][B][50], this dir writes cols dir*25..+25
  const int dir = blockIdx.x & 1;
  const int b = blockIdx.x >> 1;
  const int lane = threadIdx.x;
  const int l = (lane < 50) ? lane : 0;   // active lanes 0..49
  const bool isA = (l < 25);              // true: gates i,g ; false: gates f,o
  const int n = isA ? l : (l - 25);       // cell index
  const bool writer = (lane >= 25) && (lane < 50);
  const int qA = l;          // gate row: i_n (l<25) or f_n (l in [25,50))
  const int qB = l + 50;     // gate row: g_n or o_n

  __shared__ __align__(16) float h_lds[28];

  // per-lane weights: 2 rows of 25 (register-resident; ~110 VGPR total)
  const float* wb = w_hh + (size_t)dir * G4 * 25;
  float wA[25], wB[25];
#pragma unroll
  for (int k = 0; k < 25; ++k) {
    wA[k] = wb[qA * 25 + k];
    wB[k] = wb[qB * 25 + k];
  }

  float h[25], c = 0.f;
#pragma unroll
  for (int k = 0; k < 25; ++k) h[k] = 0.f;

  const float* xbase = xg + (size_t)dir * T_LEN * BATCH * G4 + (size_t)b * G4;
  auto xrow = [&](int s) -> const float* {
    int ss = min(s, T_LEN - 1);
    int tt = dir ? (T_LEN - 1 - ss) : ss;
    return xbase + (size_t)tt * (BATCH * G4);
  };

  // depth-3 prefetch (step ~330 cyc; cover ~900 cyc HBM latency)
  float pf[3][2];
#pragma unroll
  for (int d = 0; d < 3; ++d) {
    const float* r = xrow(d);
    pf[d][0] = r[qA];
    pf[d][1] = r[qB];
  }

  for (int s = 0; s < T_LEN; s += 3) {
#pragma unroll
    for (int d = 0; d < 3; ++d) {
      float pA = pf[d][0], pB = pf[d][1];
      {  // issue next prefetch before the dependent chain
        const float* nr = xrow(s + d + 3);
        pf[d][0] = nr[qA];
        pf[d][1] = nr[qB];
      }
#pragma unroll
      for (int k = 0; k < 25; ++k) {
        pA = fmaf(wA[k], h[k], pA);
        pB = fmaf(wB[k], h[k], pB);
      }
      // activations: aA = sigm always (i or f); bg = tanh(g) or sigm(o)
      float aA = sigm(pA);
      float xb = isA ? (pB + pB) : pB;
      float sb = sigm(xb);
      float bg = isA ? fmaf(2.f, sb, -1.f) : sb;
      float u = aA * bg;                          // i*g on lanes 0..24
      float uu = __shfl(u, isA ? l : (l - 25));   // c-lanes fetch u_n
      c = fmaf(aA, c, uu);                        // f*c + i*g  (c-lanes)
      float hn = bg * tanh_f(c);                  // o * tanh(c)
      if (writer) {
        int tt = dir ? (T_LEN - 1 - (s + d)) : (s + d);
        h_lds[n] = hn;
        hout[((size_t)tt * BATCH + b) * 50 + dir * 25 + n] = hn;
      }
      asm volatile("s_waitcnt lgkmcnt(0)" ::: "memory");
      float4 v0 = *(const float4*)&h_lds[0];
      float4 v1 = *(const float4*)&h_lds[4];
      float4 v2 = *(const float4*)&h_lds[8];
      float4 v3 = *(const float4*)&h_lds[12];
      float4 v4 = *(const float4*)&h_lds[16];
      float4 v5 = *(const float4*)&h_lds[20];
      float h24 = h_lds[24];
      h[0] = v0.x;  h[1] = v0.y;  h[2] = v0.z;  h[3] = v0.w;
      h[4] = v1.x;  h[5] = v1.y;  h[6] = v1.z;  h[7] = v1.w;
      h[8] = v2.x;  h[9] = v2.y;  h[10] = v2.z; h[11] = v2.w;
      h[12] = v3.x; h[13] = v3.y; h[14] = v3.z; h[15] = v3.w;
      h[16] = v4.x; h[17] = v4.y; h[18] = v4.z; h[19] = v4.w;
      h[20] = v5.x; h[21] = v5.y; h[22] = v5.z; h[23] = v5.w;
      h[24] = h24;
    }
  }
}

// ---------------------------------------------------------------------------
// FC: out[b][t][m] = sum_j h[t][b][j] * fc_w[m][j] + fc_b[m]
// ---------------------------------------------------------------------------
__global__ __launch_bounds__(256) void fc_kernel(
    const float* __restrict__ h, const float* __restrict__ fc_w,
    const float* __restrict__ fc_b, float* __restrict__ out) {
  int row = blockIdx.x * 256 + threadIdx.x;  // row = t*B + b
  if (row >= T_LEN * BATCH) return;
  int t = row >> 6, b = row & 63;
  const float* hr = h + (size_t)row * 50;
  float a0 = fc_b[0], a1 = fc_b[1], a2 = fc_b[2];
#pragma unroll
  for (int j = 0; j < 50; ++j) {
    float v = hr[j];
    a0 = fmaf(v, fc_w[j], a0);
    a1 = fmaf(v, fc_w[50 + j], a1);
    a2 = fmaf(v, fc_w[100 + j], a2);
  }
  float* op = out + ((size_t)b * T_LEN + t) * 3;
  op[0] = a0; op[1] = a1; op[2] = a2;
}

// ---------------------------------------------------------------------------
extern "C" void kernel_launch(void* const* d_in, const int* in_sizes, int n_in,
                              void* d_out, int out_size, void* d_ws, size_t ws_size,
                              hipStream_t stream) {
  const float* x = (const float*)d_in[0];
  const float* w_ih[3] = {(const float*)d_in[1], (const float*)d_in[5], (const float*)d_in[9]};
  const float* w_hh[3] = {(const float*)d_in[2], (const float*)d_in[6], (const float*)d_in[10]};
  const float* b_ih[3] = {(const float*)d_in[3], (const float*)d_in[7], (const float*)d_in[11]};
  const float* b_hh[3] = {(const float*)d_in[4], (const float*)d_in[8], (const float*)d_in[12]};
  const float* fc_w = (const float*)d_in[13];
  const float* fc_b = (const float*)d_in[14];
  float* out = (float*)d_out;

  float* xg = (float*)d_ws;                                 // 2*T*B*100 fp32 = 153.6 MB
  float* hA = xg + (size_t)2 * T_LEN * BATCH * G4;          // T*B*50 = 38.4 MB
  float* hB = hA + (size_t)T_LEN * BATCH * 50;              // T*B*50 = 38.4 MB

  dim3 gg(T_LEN * BATCH / 64, 2), gb(256);

  // layer 0
  hipLaunchKernelGGL((gemm_xg<0>), gg, gb, 0, stream, x, w_ih[0], b_ih[0], b_hh[0], xg, 314);
  hipLaunchKernelGGL(lstm_scan, dim3(2 * BATCH), dim3(64), 0, stream, xg, w_hh[0], hA);
  // layer 1
  hipLaunchKernelGGL((gemm_xg<1>), gg, gb, 0, stream, hA, w_ih[1], b_ih[1], b_hh[1], xg, 50);
  hipLaunchKernelGGL(lstm_scan, dim3(2 * BATCH), dim3(64), 0, stream, xg, w_hh[1], hB);
  // layer 2
  hipLaunchKernelGGL((gemm_xg<1>), gg, gb, 0, stream, hB, w_ih[2], b_ih[2], b_hh[2], xg, 50);
  hipLaunchKernelGGL(lstm_scan, dim3(2 * BATCH), dim3(64), 0, stream, xg, w_hh[2], hA);
  // fc
  hipLaunchKernelGGL(fc_kernel, dim3(T_LEN * BATCH / 256), dim3(256), 0, stream, hA, fc_w, fc_b, out);
}